// Round 2
// baseline (371.286 us; speedup 1.0000x reference)
//
#include <hip/hip_runtime.h>
#include <hip/hip_bf16.h>
#include <stdint.h>

#define Bb 4
#define Ss 2048
#define Dd 1024
#define Hh 16
#define DK 64
#define BH 64
#define Mm 8192

typedef __attribute__((ext_vector_type(8))) _Float16 f16x8;
typedef __attribute__((ext_vector_type(4))) float f32x4;

__device__ __forceinline__ void gload16(const _Float16* g, _Float16* lds) {
  __builtin_amdgcn_global_load_lds((const __attribute__((address_space(1))) unsigned int*)g,
                                   (__attribute__((address_space(3))) unsigned int*)lds, 16, 0, 0);
}

// ---------------- K0a: convert activations fp32 -> fp16 ----------------
__global__ __launch_bounds__(256) void cvt_act(const float* __restrict__ q,
                                               const float* __restrict__ k,
                                               const float* __restrict__ v,
                                               _Float16* __restrict__ xq,
                                               _Float16* __restrict__ xk,
                                               _Float16* __restrict__ xv) {
  const float* src = blockIdx.z == 0 ? q : (blockIdx.z == 1 ? k : v);
  _Float16* dst = blockIdx.z == 0 ? xq : (blockIdx.z == 1 ? xk : xv);
  int i = (blockIdx.x * 256 + threadIdx.x) * 8;
  float4 a = *(const float4*)(src + i);
  float4 b = *(const float4*)(src + i + 4);
  union { f16x8 v8; _Float16 h[8]; } o;
  o.h[0] = (_Float16)a.x; o.h[1] = (_Float16)a.y; o.h[2] = (_Float16)a.z; o.h[3] = (_Float16)a.w;
  o.h[4] = (_Float16)b.x; o.h[5] = (_Float16)b.y; o.h[6] = (_Float16)b.z; o.h[7] = (_Float16)b.w;
  *(f16x8*)(dst + i) = o.v8;
}

// ---------------- K0b: convert + transpose weights: Wt[n][k] = f16(W[k][n]) ----------------
__global__ __launch_bounds__(256) void cvt_wt(const float* __restrict__ wq,
                                              const float* __restrict__ wk,
                                              const float* __restrict__ wv,
                                              _Float16* __restrict__ tq,
                                              _Float16* __restrict__ tk,
                                              _Float16* __restrict__ tv) {
  const float* w = blockIdx.z == 0 ? wq : (blockIdx.z == 1 ? wk : wv);
  _Float16* o = blockIdx.z == 0 ? tq : (blockIdx.z == 1 ? tk : tv);
  __shared__ float tile[64][65];
  int k0 = blockIdx.x * 64;
  int n0 = blockIdx.y * 64;
  int t = threadIdx.x;
  int tr = t >> 4;
  int tc = (t & 15) * 4;
  for (int i = 0; i < 4; i++) {
    int r = i * 16 + tr;
    float4 val = *(const float4*)(w + (k0 + r) * Dd + n0 + tc);
    tile[r][tc + 0] = val.x; tile[r][tc + 1] = val.y;
    tile[r][tc + 2] = val.z; tile[r][tc + 3] = val.w;
  }
  __syncthreads();
  for (int i = 0; i < 2; i++) {
    int vdx = t + 256 * i;
    int rn = vdx >> 3;
    int c8 = (vdx & 7) * 8;
    union { f16x8 v8; _Float16 h[8]; } o2;
    for (int j = 0; j < 8; j++) o2.h[j] = (_Float16)tile[c8 + j][rn];
    *(f16x8*)(o + (n0 + rn) * Dd + k0 + c8) = o2.v8;
  }
}

// ---------------- K1: projection GEMM (m97 structure) ----------------
// A [8192,1024] f16 row-major, Bt [1024n,1024k] f16, out f16 in [b,h,s,dk] layout
__global__ __launch_bounds__(256) void gemm_qkv(
    const _Float16* __restrict__ xq, const _Float16* __restrict__ xk,
    const _Float16* __restrict__ xv,
    const _Float16* __restrict__ wtq, const _Float16* __restrict__ wtk,
    const _Float16* __restrict__ wtv,
    const float* __restrict__ bq, const float* __restrict__ bk, const float* __restrict__ bv,
    _Float16* __restrict__ oq, _Float16* __restrict__ ok,
    _Float16* __restrict__ ov) {
  int z = blockIdx.z;
  const _Float16* A  = z == 0 ? xq  : (z == 1 ? xk  : xv);
  const _Float16* Bt = z == 0 ? wtq : (z == 1 ? wtk : wtv);
  const float* bias  = z == 0 ? bq  : (z == 1 ? bk  : bv);
  _Float16* out      = z == 0 ? oq  : (z == 1 ? ok  : ov);

  __shared__ _Float16 As[128 * 64];
  __shared__ _Float16 Bs[128 * 64];

  int tid = threadIdx.x;
  int w = tid >> 6;
  int l = tid & 63;
  int lr = l & 15, lk = l >> 4;
  int m0 = blockIdx.x * 128;
  int n0 = blockIdx.y * 128;
  int wr = (w >> 1) * 64;
  int wc = (w & 1) * 64;

  f32x4 acc[4][4] = {};

  for (int kt = 0; kt < Dd; kt += 64) {
    __syncthreads();
    for (int i = 0; i < 4; i++) {
      int fbase = i * 256 + w * 64;     // wave-uniform chunk base
      int f = fbase + l;
      int r = f >> 3, c = (f & 7) * 8;
      gload16(A + (m0 + r) * Dd + kt + c, &As[fbase * 8]);
      gload16(Bt + (n0 + r) * Dd + kt + c, &Bs[fbase * 8]);
    }
    __syncthreads();
    for (int kh = 0; kh < 2; kh++) {
      f16x8 af[4], bfr[4];
      for (int mi = 0; mi < 4; mi++)
        af[mi] = *(const f16x8*)&As[(wr + mi * 16 + lr) * 64 + kh * 32 + lk * 8];
      for (int ni = 0; ni < 4; ni++)
        bfr[ni] = *(const f16x8*)&Bs[(wc + ni * 16 + lr) * 64 + kh * 32 + lk * 8];
      for (int mi = 0; mi < 4; mi++)
        for (int ni = 0; ni < 4; ni++)
          acc[mi][ni] = __builtin_amdgcn_mfma_f32_16x16x32_f16(af[mi], bfr[ni], acc[mi][ni], 0, 0, 0);
    }
  }

  for (int mi = 0; mi < 4; mi++) {
    for (int ni = 0; ni < 4; ni++) {
      int n = n0 + wc + ni * 16 + lr;
      float bval = bias[n];
      int h = n >> 6, dk = n & 63;
      for (int j = 0; j < 4; j++) {
        int m = m0 + wr + mi * 16 + lk * 4 + j;
        int b = m >> 11, s = m & 2047;
        out[((b * Hh + h) * Ss + s) * DK + dk] = (_Float16)(acc[mi][ni][j] + bval);
      }
    }
  }
}

// ---------------- K2: transpose V: [bh][s][dk] -> [bh][dk][s] ----------------
__global__ __launch_bounds__(256) void transpose_v(const unsigned short* __restrict__ vin,
                                                   unsigned short* __restrict__ vout) {
  __shared__ unsigned short t[64][80];  // pad to 80 (160B row, 16B-aligned)
  typedef __attribute__((ext_vector_type(8))) short s16x8;
  int bh = blockIdx.y;
  int s0 = blockIdx.x * 64;
  int tid = threadIdx.x;
  const unsigned short* vp = vin + bh * (Ss * DK);
  for (int i = 0; i < 2; i++) {
    int v = tid + 256 * i;
    int r = v >> 3, c8 = (v & 7) * 8;
    s16x8 val = *(const s16x8*)(vp + (s0 + r) * DK + c8);
    *(s16x8*)&t[r][c8] = val;
  }
  __syncthreads();
  unsigned short* op = vout + bh * (DK * Ss);
  for (int i = 0; i < 2; i++) {
    int v = tid + 256 * i;
    int rn = v >> 3;
    int c8 = (v & 7) * 8;
    union { s16x8 v8; unsigned short u[8]; } o2;
    for (int j = 0; j < 8; j++) o2.u[j] = t[c8 + j][rn];
    *(s16x8*)(op + rn * Ss + s0 + c8) = o2.v8;
  }
}

// ---------------- K3: flash attention ----------------
// Q,K: [bh][s][64] f16; Vt: [bh][64][s] f16; out fp32 [b,s,1024] = ctx + query
__global__ __launch_bounds__(256) void attn(const _Float16* __restrict__ Qb,
                                            const _Float16* __restrict__ Kb,
                                            const _Float16* __restrict__ Vt,
                                            const float* __restrict__ query,
                                            float* __restrict__ outp) {
  __shared__ _Float16 P[4][32 * 64];
  int tid = threadIdx.x;
  int w = tid >> 6, l = tid & 63;
  int lr = l & 15, lk = l >> 4;
  int bh = blockIdx.y;
  int q0 = blockIdx.x * 128 + w * 32;
  const _Float16* Qp = Qb + bh * (Ss * DK);
  const _Float16* Kp = Kb + bh * (Ss * DK);
  const _Float16* Vp = Vt + bh * (DK * Ss);

  f16x8 qf[2][2];
  for (int qg = 0; qg < 2; qg++)
    for (int kf = 0; kf < 2; kf++)
      qf[qg][kf] = *(const f16x8*)(Qp + (q0 + qg * 16 + lr) * DK + kf * 32 + lk * 8);

  f32x4 o[2][4] = {};
  float mrun[2][4], lrun[2][4];
  for (int qg = 0; qg < 2; qg++)
    for (int j = 0; j < 4; j++) { mrun[qg][j] = -1e30f; lrun[qg][j] = 0.f; }

  _Float16* Pw = &P[w][0];
  const f32x4 fz = {0.f, 0.f, 0.f, 0.f};

  for (int kv0 = 0; kv0 < Ss; kv0 += 64) {
    f16x8 kb[4][2];
    for (int kg = 0; kg < 4; kg++)
      for (int kf = 0; kf < 2; kf++)
        kb[kg][kf] = *(const f16x8*)(Kp + (kv0 + kg * 16 + lr) * DK + kf * 32 + lk * 8);

    f32x4 sc[2][4];
    for (int qg = 0; qg < 2; qg++)
      for (int kg = 0; kg < 4; kg++) {
        f32x4 t0 = __builtin_amdgcn_mfma_f32_16x16x32_f16(qf[qg][0], kb[kg][0], fz, 0, 0, 0);
        sc[qg][kg] = __builtin_amdgcn_mfma_f32_16x16x32_f16(qf[qg][1], kb[kg][1], t0, 0, 0, 0);
      }

    // online softmax (row state replicated across the 16-lane group)
    for (int qg = 0; qg < 2; qg++) {
      for (int j = 0; j < 4; j++) {
        float t = fmaxf(fmaxf(sc[qg][0][j], sc[qg][1][j]), fmaxf(sc[qg][2][j], sc[qg][3][j]));
        t = fmaxf(t, __shfl_xor(t, 1));
        t = fmaxf(t, __shfl_xor(t, 2));
        t = fmaxf(t, __shfl_xor(t, 4));
        t = fmaxf(t, __shfl_xor(t, 8));
        float mn = fmaxf(mrun[qg][j], t);
        float scale = __expf(mrun[qg][j] - mn);
        mrun[qg][j] = mn;
        lrun[qg][j] *= scale;
        for (int dg = 0; dg < 4; dg++) o[qg][dg][j] *= scale;
        float rs = 0.f;
        for (int kg = 0; kg < 4; kg++) {
          float p = __expf(sc[qg][kg][j] - mn);
          sc[qg][kg][j] = p;
          rs += p;
        }
        rs += __shfl_xor(rs, 1);
        rs += __shfl_xor(rs, 2);
        rs += __shfl_xor(rs, 4);
        rs += __shfl_xor(rs, 8);
        lrun[qg][j] += rs;
      }
    }

    // P -> LDS (f16, XOR-swizzled to kill 128B-stride bank conflicts)
    for (int qg = 0; qg < 2; qg++)
      for (int kg = 0; kg < 4; kg++)
        for (int j = 0; j < 4; j++) {
          int q = qg * 16 + lk * 4 + j;
          int kv = kg * 16 + lr;
          Pw[q * 64 + (kv ^ ((q & 7) << 3))] = (_Float16)sc[qg][kg][j];
        }
    asm volatile("s_waitcnt lgkmcnt(0)" ::: "memory");
    __builtin_amdgcn_sched_barrier(0);

    f16x8 pa[2][2];
    for (int qg = 0; qg < 2; qg++)
      for (int kk = 0; kk < 2; kk++) {
        int q = qg * 16 + lr;
        int kv = kk * 32 + lk * 8;
        pa[qg][kk] = *(const f16x8*)&Pw[q * 64 + (kv ^ ((q & 7) << 3))];
      }
    for (int dg = 0; dg < 4; dg++)
      for (int kk = 0; kk < 2; kk++) {
        f16x8 vb = *(const f16x8*)(Vp + (dg * 16 + lr) * Ss + kv0 + kk * 32 + lk * 8);
        for (int qg = 0; qg < 2; qg++)
          o[qg][dg] = __builtin_amdgcn_mfma_f32_16x16x32_f16(pa[qg][kk], vb, o[qg][dg], 0, 0, 0);
      }
  }

  int b = bh >> 4, h = bh & 15;
  for (int qg = 0; qg < 2; qg++)
    for (int j = 0; j < 4; j++) {
      float inv = 1.f / lrun[qg][j];
      int qglob = q0 + qg * 16 + lk * 4 + j;
      for (int dg = 0; dg < 4; dg++) {
        int d = h * 64 + dg * 16 + lr;
        int idx = (b * Ss + qglob) * Dd + d;
        outp[idx] = o[qg][dg][j] * inv + query[idx];
      }
    }
}

extern "C" void kernel_launch(void* const* d_in, const int* in_sizes, int n_in,
                              void* d_out, int out_size, void* d_ws, size_t ws_size,
                              hipStream_t stream) {
  const float* query = (const float*)d_in[0];
  const float* key   = (const float*)d_in[1];
  const float* value = (const float*)d_in[2];
  const float* Wq = (const float*)d_in[3];
  const float* bq = (const float*)d_in[4];
  const float* Wk = (const float*)d_in[5];
  const float* bk = (const float*)d_in[6];
  const float* Wv = (const float*)d_in[7];
  const float* bv = (const float*)d_in[8];
  float* out = (float*)d_out;

  _Float16* ws = (_Float16*)d_ws;
  const size_t ACT = (size_t)Mm * Dd;       // 8388608 elems
  const size_t WSZ = (size_t)Dd * Dd;       // 1048576 elems
  _Float16* Xq   = ws;
  _Float16* Xk   = Xq + ACT;
  _Float16* Xv   = Xk + ACT;
  _Float16* Wtq  = Xv + ACT;
  _Float16* Wtk  = Wtq + WSZ;
  _Float16* Wtv  = Wtk + WSZ;
  _Float16* Qb   = Wtv + WSZ;
  _Float16* Kb   = Qb + ACT;
  _Float16* Vtmp = Kb + ACT;
  _Float16* VtT  = Vtmp + ACT;

  cvt_act<<<dim3(4096, 1, 3), dim3(256), 0, stream>>>(query, key, value, Xq, Xk, Xv);
  cvt_wt<<<dim3(16, 16, 3), dim3(256), 0, stream>>>(Wq, Wk, Wv, Wtq, Wtk, Wtv);
  gemm_qkv<<<dim3(64, 8, 3), dim3(256), 0, stream>>>(Xq, Xk, Xv, Wtq, Wtk, Wtv,
                                                     bq, bk, bv, Qb, Kb, Vtmp);
  transpose_v<<<dim3(32, 64), dim3(256), 0, stream>>>((const unsigned short*)Vtmp,
                                                      (unsigned short*)VtT);
  attn<<<dim3(16, 64), dim3(256), 0, stream>>>(Qb, Kb, VtT, query, out);
}